// Round 1
// baseline (409.138 us; speedup 1.0000x reference)
//
#include <hip/hip_runtime.h>

#define NN 8192
#define DD 256
#define RCAP 1024   // per-row LDS capacity for (j, e) pairs

typedef float v4f __attribute__((ext_vector_type(4)));
typedef unsigned short u16x4 __attribute__((ext_vector_type(4)));
typedef unsigned short u16x8 __attribute__((ext_vector_type(8)));

__device__ __forceinline__ unsigned short f2bf_rne(float x) {
    unsigned u = __float_as_uint(x);
    u += 0x7fffu + ((u >> 16) & 1u);
    return (unsigned short)(u >> 16);
}

// Fused prep: scores[row] = inputs[row,:].Hv AND (optionally) bf16 copy of inputs.
template <bool WRITE_IB>
__global__ __launch_bounds__(256) void prep_kernel(const float* __restrict__ inputs,
                                                   const float* __restrict__ Hv,
                                                   float* __restrict__ scores,
                                                   unsigned short* __restrict__ ib) {
    int wave = threadIdx.x >> 6;
    int lane = threadIdx.x & 63;
    int row  = blockIdx.x * 4 + wave;
    float4 v = ((const float4*)(inputs + (size_t)row * DD))[lane];
    if (WRITE_IB) {
        u16x4 u;
        u.x = f2bf_rne(v.x); u.y = f2bf_rne(v.y); u.z = f2bf_rne(v.z); u.w = f2bf_rne(v.w);
        ((u16x4*)(ib + (size_t)row * DD))[lane] = u;
    }
    float4 h = ((const float4*)Hv)[lane];
    float s = v.x * h.x + v.y * h.y + v.z * h.z + v.w * h.w;
    #pragma unroll
    for (int off = 32; off > 0; off >>= 1) s += __shfl_down(s, off, 64);
    if (lane == 0) scores[row] = s;
}

// ---------------- Fused build+gather ----------------
// Dual-row gather: lanes 0-31 handle even entries, lanes 32-63 odd entries.
// Each lane loads u16x8 (16 B) -> 1 KB per wave instruction, 2 rows per load wave.
__device__ __forceinline__ void batch8x2(const unsigned short* __restrict__ ib,
                                         int jl, int el, int m, int sel, int lane8,
                                         float4& accL, float4& accH, float& ssum) {
    int js[8]; float es[8];
#pragma unroll
    for (int u = 0; u < 8; ++u) {
        js[u] = __builtin_amdgcn_readlane(jl, m + u);
        es[u] = __uint_as_float(__builtin_amdgcn_readlane(el, m + u));
    }
    u16x8 g[4];
#pragma unroll
    for (int p = 0; p < 4; ++p) {
        int j = sel ? js[2 * p + 1] : js[2 * p];
        g[p] = *(const u16x8*)(ib + (size_t)j * DD + lane8);
    }
#pragma unroll
    for (int p = 0; p < 4; ++p) {
        float e = sel ? es[2 * p + 1] : es[2 * p];
        float4 lo, hi;
        lo.x = __uint_as_float((unsigned)g[p][0] << 16);
        lo.y = __uint_as_float((unsigned)g[p][1] << 16);
        lo.z = __uint_as_float((unsigned)g[p][2] << 16);
        lo.w = __uint_as_float((unsigned)g[p][3] << 16);
        hi.x = __uint_as_float((unsigned)g[p][4] << 16);
        hi.y = __uint_as_float((unsigned)g[p][5] << 16);
        hi.z = __uint_as_float((unsigned)g[p][6] << 16);
        hi.w = __uint_as_float((unsigned)g[p][7] << 16);
        accL.x += e * lo.x; accL.y += e * lo.y; accL.z += e * lo.z; accL.w += e * lo.w;
        accH.x += e * hi.x; accH.y += e * hi.y; accH.z += e * hi.z; accH.w += e * hi.w;
        ssum += e;
    }
}

// Per-wave gather over entry range [b, ke) of the LDS (j, e) list.
__device__ __forceinline__ void gather_range(const float2* __restrict__ s_je, int b, int ke,
                                             const unsigned short* __restrict__ ib, int lane,
                                             float4& accL, float4& accH, float& ssum) {
    const int sel   = lane >> 5;
    const int lane8 = (lane & 31) * 8;
    while (b < ke) {
        int n = ke - b; n = n > 64 ? 64 : n;
        float2 je = s_je[b + (lane < n ? lane : 0)];
        if (lane >= n) je.y = 0.f;   // padded entries contribute e = 0
        int jl = __float_as_int(je.x);
        int el = __float_as_int(je.y);
        int n8 = (n + 7) & ~7;
        for (int m = 0; m < n8; m += 8)
            batch8x2(ib, jl, el, m, sel, lane8, accL, accH, ssum);
        b += n;
    }
}

// One row per block. Scan adj row from registers -> compact (j, exp(a*score)) to
// LDS -> gather bf16 input rows. Build (HBM stream) and gather (L2/VALU) of
// different blocks overlap on the same CU.
__global__ __launch_bounds__(256) void fused_kernel(const float* __restrict__ adj,
                                                    const float* __restrict__ scores,
                                                    const unsigned short* __restrict__ ib,
                                                    float* __restrict__ out) {
    __shared__ float2 s_je[RCAP];       // 8 KB
    __shared__ float  s_red[8 * DD];    // 8 KB: 4 waves x 2 halves, full-row partials
    __shared__ float  s_ss[8];
    __shared__ int    s_wsum[4];
    __shared__ int    s_cnt;

    const int tid  = threadIdx.x;
    const int lane = tid & 63;
    const int wave = tid >> 6;
    const int row  = blockIdx.x;

    const v4f* p = (const v4f*)(adj + (size_t)row * NN);
    v4f a[8];
#pragma unroll
    for (int c = 0; c < 8; ++c) a[c] = __builtin_nontemporal_load(&p[c * 256 + tid]);

    int nz = 0;
#pragma unroll
    for (int c = 0; c < 8; ++c)
        nz += (a[c].x != 0.f) + (a[c].y != 0.f) + (a[c].z != 0.f) + (a[c].w != 0.f);
    int pre = nz;
#pragma unroll
    for (int off = 1; off < 64; off <<= 1) {
        int t = __shfl_up(pre, off, 64);
        if (lane >= off) pre += t;
    }
    if (lane == 63) s_wsum[wave] = pre;
    __syncthreads();
    int base = 0, total = 0;
#pragma unroll
    for (int w = 0; w < 4; ++w) {
        int t = s_wsum[w];
        if (w < wave) base += t;
        total += t;
    }

    float4 accL = make_float4(0.f, 0.f, 0.f, 0.f), accH = accL;
    float ssum = 0.f;

    if (total <= RCAP) {
        // Compact with exp fused (scores is 32 KB, cache-resident).
        int off = base + pre - nz;
#pragma unroll
        for (int c = 0; c < 8; ++c) {
            int j0 = c * 1024 + tid * 4;
            float v;
            v = a[c].x; if (v != 0.f) { s_je[off] = make_float2(__int_as_float(j0 + 0), __expf(v * scores[j0 + 0])); off++; }
            v = a[c].y; if (v != 0.f) { s_je[off] = make_float2(__int_as_float(j0 + 1), __expf(v * scores[j0 + 1])); off++; }
            v = a[c].z; if (v != 0.f) { s_je[off] = make_float2(__int_as_float(j0 + 2), __expf(v * scores[j0 + 2])); off++; }
            v = a[c].w; if (v != 0.f) { s_je[off] = make_float2(__int_as_float(j0 + 3), __expf(v * scores[j0 + 3])); off++; }
        }
        __syncthreads();
        gather_range(s_je, wave * total / 4, (wave + 1) * total / 4, ib, lane, accL, accH, ssum);
    } else {
        // Any-density fallback: per-1024-column slab compact + gather. Block-uniform.
        for (int c = 0; c < 8; ++c) {
            if (tid == 0) s_cnt = 0;
            __syncthreads();
            int j0 = c * 1024 + tid * 4;
            float v;
            v = a[c].x; if (v != 0.f) { int k = atomicAdd(&s_cnt, 1); s_je[k] = make_float2(__int_as_float(j0 + 0), __expf(v * scores[j0 + 0])); }
            v = a[c].y; if (v != 0.f) { int k = atomicAdd(&s_cnt, 1); s_je[k] = make_float2(__int_as_float(j0 + 1), __expf(v * scores[j0 + 1])); }
            v = a[c].z; if (v != 0.f) { int k = atomicAdd(&s_cnt, 1); s_je[k] = make_float2(__int_as_float(j0 + 2), __expf(v * scores[j0 + 2])); }
            v = a[c].w; if (v != 0.f) { int k = atomicAdd(&s_cnt, 1); s_je[k] = make_float2(__int_as_float(j0 + 3), __expf(v * scores[j0 + 3])); }
            __syncthreads();
            int tc = s_cnt;
            gather_range(s_je, wave * tc / 4, (wave + 1) * tc / 4, ib, lane, accL, accH, ssum);
            __syncthreads();
        }
    }

    // Reduce 8 partial rows (4 waves x 2 lane-halves; each half covers all 256 ch).
    const int half = wave * 2 + (lane >> 5);
    const int l8   = (lane & 31) * 8;
    if ((lane & 31) == 0) s_ss[half] = ssum;
    *(float4*)&s_red[half * DD + l8]     = accL;
    *(float4*)&s_red[half * DD + l8 + 4] = accH;
    __syncthreads();
    float tot = 0.f;
#pragma unroll
    for (int i = 0; i < 8; ++i) tot += s_ss[i];
    float r = 0.f;
#pragma unroll
    for (int i = 0; i < 8; ++i) r += s_red[i * DD + tid];
    out[(size_t)row * DD + tid] = (tot > 0.f) ? r / tot : 0.f;
}

// Compact fallback if ws is too small (not expected).
__global__ __launch_bounds__(256) void attn_fallback(const float* __restrict__ adj,
                                                     const float* __restrict__ inputs,
                                                     const float* __restrict__ scores,
                                                     float* __restrict__ out) {
    __shared__ int   s_j[1024];
    __shared__ float s_e[1024];
    __shared__ int   s_cnt;
    const int row = blockIdx.x;
    const int tid = threadIdx.x;
    const float* arow = adj + (size_t)row * NN;
    float acc = 0.f, ssum = 0.f;
    for (int base = 0; base < NN; base += 1024) {
        if (tid == 0) s_cnt = 0;
        __syncthreads();
        float4 a = ((const float4*)(arow + base))[tid];
        int j0 = base + tid * 4;
        if (a.x != 0.f) { int k = atomicAdd(&s_cnt, 1); s_j[k] = j0 + 0; s_e[k] = __expf(a.x * scores[j0 + 0]); }
        if (a.y != 0.f) { int k = atomicAdd(&s_cnt, 1); s_j[k] = j0 + 1; s_e[k] = __expf(a.y * scores[j0 + 1]); }
        if (a.z != 0.f) { int k = atomicAdd(&s_cnt, 1); s_j[k] = j0 + 2; s_e[k] = __expf(a.z * scores[j0 + 2]); }
        if (a.w != 0.f) { int k = atomicAdd(&s_cnt, 1); s_j[k] = j0 + 3; s_e[k] = __expf(a.w * scores[j0 + 3]); }
        __syncthreads();
        int c = s_cnt;
        for (int k = 0; k < c; ++k) {
            float e = s_e[k];
            acc  += e * inputs[(size_t)s_j[k] * DD + tid];
            ssum += e;
        }
        __syncthreads();
    }
    out[(size_t)row * DD + tid] = (ssum > 0.f) ? acc / ssum : 0.f;
}

extern "C" void kernel_launch(void* const* d_in, const int* in_sizes, int n_in,
                              void* d_out, int out_size, void* d_ws, size_t ws_size,
                              hipStream_t stream) {
    const float* inputs = (const float*)d_in[0];  // [N, D] fp32
    const float* adj    = (const float*)d_in[1];  // [N, N] fp32
    const float* Hv     = (const float*)d_in[2];  // [D, 1] fp32
    float* out = (float*)d_out;                   // [N, D] fp32

    char* ws = (char*)d_ws;
    float*          scores = (float*)ws;                    // 32 KB
    unsigned short* ib     = (unsigned short*)(ws + 32768); // 4 MB

    const size_t need = 32768 + (size_t)NN * DD * 2;

    if (ws_size >= need) {
        prep_kernel<true><<<NN / 4, 256, 0, stream>>>(inputs, Hv, scores, ib);
        fused_kernel<<<NN, 256, 0, stream>>>(adj, scores, ib, out);
    } else {
        prep_kernel<false><<<NN / 4, 256, 0, stream>>>(inputs, Hv, scores, nullptr);
        attn_fallback<<<NN, 256, 0, stream>>>(adj, inputs, scores, out);
    }
}

// Round 2
// 405.817 us; speedup vs baseline: 1.0082x; 1.0082x over previous
//
#include <hip/hip_runtime.h>

#define NN 8192
#define DD 256
#define WCOLS 2048   // adj columns per wave (quarter row)
#define WCAP 256     // per-wave entry capacity, main path
#define WSEG 264     // per-wave LDS segment stride (WCAP + pad-to-8 headroom)

typedef float v4f __attribute__((ext_vector_type(4)));
typedef unsigned short u16x4 __attribute__((ext_vector_type(4)));
typedef unsigned short u16x8 __attribute__((ext_vector_type(8)));

__device__ __forceinline__ unsigned short f2bf_rne(float x) {
    unsigned u = __float_as_uint(x);
    u += 0x7fffu + ((u >> 16) & 1u);
    return (unsigned short)(u >> 16);
}

// Fused prep: scores[row] = inputs[row,:].Hv AND (optionally) bf16 copy of inputs.
template <bool WRITE_IB>
__global__ __launch_bounds__(256) void prep_kernel(const float* __restrict__ inputs,
                                                   const float* __restrict__ Hv,
                                                   float* __restrict__ scores,
                                                   unsigned short* __restrict__ ib) {
    int wave = threadIdx.x >> 6;
    int lane = threadIdx.x & 63;
    int row  = blockIdx.x * 4 + wave;
    float4 v = ((const float4*)(inputs + (size_t)row * DD))[lane];
    if (WRITE_IB) {
        u16x4 u;
        u.x = f2bf_rne(v.x); u.y = f2bf_rne(v.y); u.z = f2bf_rne(v.z); u.w = f2bf_rne(v.w);
        ((u16x4*)(ib + (size_t)row * DD))[lane] = u;
    }
    float4 h = ((const float4*)Hv)[lane];
    float s = v.x * h.x + v.y * h.y + v.z * h.z + v.w * h.w;
    #pragma unroll
    for (int off = 32; off > 0; off >>= 1) s += __shfl_down(s, off, 64);
    if (lane == 0) scores[row] = s;
}

// ---------------- Fused build+gather, wave-local ----------------
// Gather a wave-local LDS segment [0, n8) (n8 % 8 == 0, padded with e=0).
// Dual-entry scheme: lanes 0-31 (sel=0) process even entries, lanes 32-63 odd.
// (j, e) broadcast is a uniform-address LDS read (2 distinct addrs/wave: free).
// Each half-wave loads 512 B of one bf16 input row per entry (16 B/lane).
__device__ __forceinline__ void gather_seg(const float2* __restrict__ s_seg, int n8,
                                           const unsigned short* __restrict__ ib,
                                           int sel, int lane8,
                                           float4& accL, float4& accH, float& ssum) {
    for (int m = 0; m < n8; m += 8) {
        float2 je[4];
#pragma unroll
        for (int p = 0; p < 4; ++p) je[p] = s_seg[m + 2 * p + sel];
        u16x8 g[4];
#pragma unroll
        for (int p = 0; p < 4; ++p)
            g[p] = *(const u16x8*)(ib + (size_t)__float_as_int(je[p].x) * DD + lane8);
#pragma unroll
        for (int p = 0; p < 4; ++p) {
            float e = je[p].y;
            accL.x += e * __uint_as_float((unsigned)g[p][0] << 16);
            accL.y += e * __uint_as_float((unsigned)g[p][1] << 16);
            accL.z += e * __uint_as_float((unsigned)g[p][2] << 16);
            accL.w += e * __uint_as_float((unsigned)g[p][3] << 16);
            accH.x += e * __uint_as_float((unsigned)g[p][4] << 16);
            accH.y += e * __uint_as_float((unsigned)g[p][5] << 16);
            accH.z += e * __uint_as_float((unsigned)g[p][6] << 16);
            accH.w += e * __uint_as_float((unsigned)g[p][7] << 16);
            ssum += e;
        }
    }
}

// One row per block, one 2048-col quarter per wave. Common path has NO block
// barriers: each wave counts/compacts/gathers its own quarter; single final
// __syncthreads() for the 8-partial reduce. Build (HBM stream) of some blocks
// overlaps gather (L2/VALU) of others on the same CU.
__global__ __launch_bounds__(256) void fused_kernel(const float* __restrict__ adj,
                                                    const float* __restrict__ scores,
                                                    const unsigned short* __restrict__ ib,
                                                    float* __restrict__ out) {
    __shared__ float2 s_je[4][WSEG];   // ~8.3 KB
    __shared__ float  s_red[8 * DD];   // 8 KB
    __shared__ float  s_ss[8];

    const int tid   = threadIdx.x;
    const int lane  = tid & 63;
    const int wave  = tid >> 6;
    const int row   = blockIdx.x;
    const int sel   = lane >> 5;
    const int lane8 = (lane & 31) * 8;
    const int colbase = wave * WCOLS + lane * 4;

    const float* arow = adj + (size_t)row * NN;
    v4f a[8];
#pragma unroll
    for (int c = 0; c < 8; ++c)
        a[c] = __builtin_nontemporal_load(((const v4f*)(arow + wave * WCOLS + c * 256)) + lane);

    int nz = 0;
#pragma unroll
    for (int c = 0; c < 8; ++c)
        nz += (a[c].x != 0.f) + (a[c].y != 0.f) + (a[c].z != 0.f) + (a[c].w != 0.f);
    int pre = nz;
#pragma unroll
    for (int off = 1; off < 64; off <<= 1) {
        int t = __shfl_up(pre, off, 64);
        if (lane >= off) pre += t;
    }
    const int total = __shfl(pre, 63, 64);

    float4 accL = make_float4(0.f, 0.f, 0.f, 0.f), accH = accL;
    float ssum = 0.f;
    float2* seg = s_je[wave];

    if (total <= WCAP) {
        // Wave-local compact with exp fused (scores: 32 KB, cache-resident).
        int off = pre - nz;
#pragma unroll
        for (int c = 0; c < 8; ++c) {
            int j0 = colbase + c * 256;
            float v;
            v = a[c].x; if (v != 0.f) { seg[off] = make_float2(__int_as_float(j0 + 0), __expf(v * scores[j0 + 0])); off++; }
            v = a[c].y; if (v != 0.f) { seg[off] = make_float2(__int_as_float(j0 + 1), __expf(v * scores[j0 + 1])); off++; }
            v = a[c].z; if (v != 0.f) { seg[off] = make_float2(__int_as_float(j0 + 2), __expf(v * scores[j0 + 2])); off++; }
            v = a[c].w; if (v != 0.f) { seg[off] = make_float2(__int_as_float(j0 + 3), __expf(v * scores[j0 + 3])); off++; }
        }
        const int n8 = (total + 7) & ~7;
        if (lane < n8 - total) seg[total + lane] = make_float2(0.f, 0.f);  // e=0 pad
        asm volatile("s_waitcnt lgkmcnt(0)" ::: "memory");
        __builtin_amdgcn_sched_barrier(0);
        gather_seg(seg, n8, ib, sel, lane8, accL, accH, ssum);
    } else {
        // Any-density fallback: per-256-col chunk compact+gather, still wave-local
        // (chunk nz <= 256 always fits). Divergence across waves is fine: no barriers.
        for (int c = 0; c < 8; ++c) {
            int cn = (a[c].x != 0.f) + (a[c].y != 0.f) + (a[c].z != 0.f) + (a[c].w != 0.f);
            int cpre = cn;
#pragma unroll
            for (int off = 1; off < 64; off <<= 1) {
                int t = __shfl_up(cpre, off, 64);
                if (lane >= off) cpre += t;
            }
            int ctotal = __shfl(cpre, 63, 64);
            int off = cpre - cn;
            int j0 = colbase + c * 256;
            float v;
            v = a[c].x; if (v != 0.f) { seg[off] = make_float2(__int_as_float(j0 + 0), __expf(v * scores[j0 + 0])); off++; }
            v = a[c].y; if (v != 0.f) { seg[off] = make_float2(__int_as_float(j0 + 1), __expf(v * scores[j0 + 1])); off++; }
            v = a[c].z; if (v != 0.f) { seg[off] = make_float2(__int_as_float(j0 + 2), __expf(v * scores[j0 + 2])); off++; }
            v = a[c].w; if (v != 0.f) { seg[off] = make_float2(__int_as_float(j0 + 3), __expf(v * scores[j0 + 3])); off++; }
            int cn8 = (ctotal + 7) & ~7;
            if (lane < cn8 - ctotal) seg[ctotal + lane] = make_float2(0.f, 0.f);
            asm volatile("s_waitcnt lgkmcnt(0)" ::: "memory");
            __builtin_amdgcn_sched_barrier(0);
            gather_seg(seg, cn8, ib, sel, lane8, accL, accH, ssum);
            asm volatile("s_waitcnt lgkmcnt(0)" ::: "memory");  // reads done before re-fill
            __builtin_amdgcn_sched_barrier(0);
        }
    }

    // Reduce 8 partial rows (4 waves x 2 halves; each half covers all 256 ch).
    const int half = wave * 2 + sel;
    if ((lane & 31) == 0) s_ss[half] = ssum;
    *(float4*)&s_red[half * DD + lane8]     = accL;
    *(float4*)&s_red[half * DD + lane8 + 4] = accH;
    __syncthreads();
    float tot = 0.f;
#pragma unroll
    for (int i = 0; i < 8; ++i) tot += s_ss[i];
    float r = 0.f;
#pragma unroll
    for (int i = 0; i < 8; ++i) r += s_red[i * DD + tid];
    out[(size_t)row * DD + tid] = (tot > 0.f) ? r / tot : 0.f;
}

// Compact fallback if ws is too small (not expected).
__global__ __launch_bounds__(256) void attn_fallback(const float* __restrict__ adj,
                                                     const float* __restrict__ inputs,
                                                     const float* __restrict__ scores,
                                                     float* __restrict__ out) {
    __shared__ int   s_j[1024];
    __shared__ float s_e[1024];
    __shared__ int   s_cnt;
    const int row = blockIdx.x;
    const int tid = threadIdx.x;
    const float* arow = adj + (size_t)row * NN;
    float acc = 0.f, ssum = 0.f;
    for (int base = 0; base < NN; base += 1024) {
        if (tid == 0) s_cnt = 0;
        __syncthreads();
        float4 a = ((const float4*)(arow + base))[tid];
        int j0 = base + tid * 4;
        if (a.x != 0.f) { int k = atomicAdd(&s_cnt, 1); s_j[k] = j0 + 0; s_e[k] = __expf(a.x * scores[j0 + 0]); }
        if (a.y != 0.f) { int k = atomicAdd(&s_cnt, 1); s_j[k] = j0 + 1; s_e[k] = __expf(a.y * scores[j0 + 1]); }
        if (a.z != 0.f) { int k = atomicAdd(&s_cnt, 1); s_j[k] = j0 + 2; s_e[k] = __expf(a.z * scores[j0 + 2]); }
        if (a.w != 0.f) { int k = atomicAdd(&s_cnt, 1); s_j[k] = j0 + 3; s_e[k] = __expf(a.w * scores[j0 + 3]); }
        __syncthreads();
        int c = s_cnt;
        for (int k = 0; k < c; ++k) {
            float e = s_e[k];
            acc  += e * inputs[(size_t)s_j[k] * DD + tid];
            ssum += e;
        }
        __syncthreads();
    }
    out[(size_t)row * DD + tid] = (ssum > 0.f) ? acc / ssum : 0.f;
}

extern "C" void kernel_launch(void* const* d_in, const int* in_sizes, int n_in,
                              void* d_out, int out_size, void* d_ws, size_t ws_size,
                              hipStream_t stream) {
    const float* inputs = (const float*)d_in[0];  // [N, D] fp32
    const float* adj    = (const float*)d_in[1];  // [N, N] fp32
    const float* Hv     = (const float*)d_in[2];  // [D, 1] fp32
    float* out = (float*)d_out;                   // [N, D] fp32

    char* ws = (char*)d_ws;
    float*          scores = (float*)ws;                    // 32 KB
    unsigned short* ib     = (unsigned short*)(ws + 32768); // 4 MB

    const size_t need = 32768 + (size_t)NN * DD * 2;

    if (ws_size >= need) {
        prep_kernel<true><<<NN / 4, 256, 0, stream>>>(inputs, Hv, scores, ib);
        fused_kernel<<<NN, 256, 0, stream>>>(adj, scores, ib, out);
    } else {
        prep_kernel<false><<<NN / 4, 256, 0, stream>>>(inputs, Hv, scores, nullptr);
        attn_fallback<<<NN, 256, 0, stream>>>(adj, inputs, scores, out);
    }
}